// Round 9
// baseline (230.009 us; speedup 1.0000x reference)
//
#include <hip/hip_runtime.h>
#include <hip/hip_fp16.h>
#include <math.h>

#define H_DIM 180
#define W_DIM 360
#define CH    256
#define NHEAD 8
#define HD    32
#define MPIX  (H_DIM * W_DIM)   // 64800
#define KDIM  256

typedef _Float16 f16x8 __attribute__((ext_vector_type(8)));
typedef _Float16 h2    __attribute__((ext_vector_type(2)));
typedef float    f32x4 __attribute__((ext_vector_type(4)));

#if __has_builtin(__builtin_amdgcn_fdot2)
#define HAS_FDOT2 1
#else
#define HAS_FDOT2 0
#endif

__device__ __forceinline__ h2 pack2(float a, float b) {
#if __has_builtin(__builtin_amdgcn_cvt_pkrtz)
    return __builtin_bit_cast(h2, __builtin_amdgcn_cvt_pkrtz(a, b));
#else
    h2 r; r.x = (_Float16)a; r.y = (_Float16)b; return r;
#endif
}

// ---------------------------------------------------------------------------
// Kernel 0: weight transposes fp32 -> fp16. y=0: w_qkv -> Wqt[768][256];
// y=1: w_proj -> Wpt[256][256].  (X conversion is fused into the qkv GEMM.)
// ---------------------------------------------------------------------------
__global__ __launch_bounds__(256)
void convert_w_kernel(const float* __restrict__ Wq, const float* __restrict__ Wp,
                      _Float16* __restrict__ Wqt, _Float16* __restrict__ Wpt)
{
    const int tid = blockIdx.x * 256 + threadIdx.x;
    if (blockIdx.y == 0) {
        if (tid < 768 * 256) {
            const int n = tid >> 8, k = tid & 255;
            Wqt[tid] = (_Float16)Wq[k * 768 + n];
        }
    } else {
        if (tid < 256 * 256) {
            const int n = tid >> 8, k = tid & 255;
            Wpt[tid] = (_Float16)Wp[k * 256 + n];
        }
    }
}

// ---------------------------------------------------------------------------
// MFMA fp16 GEMM, 128x128 tile, 4 waves (64x64 each), BK=64, K=256.
// MODE 0: A = X fp32, converted to fp16 during staging (reg->cvt->ds_write);
//         epilogue: bias, q-scale, coalesced scatter to [8][M][32] q/k/v.
// MODE 1: A = fp16 (global_load_lds); epilogue: bias, fp32 out [M][NB].
// ---------------------------------------------------------------------------
template<int NB, int MODE>
__global__ __launch_bounds__(256)
void mfma_gemm_kernel(const float* __restrict__ Xf,       // MODE 0 A source
                      const _Float16* __restrict__ Ah,    // MODE 1 A source
                      const _Float16* __restrict__ Bt,
                      const float* __restrict__ bias,
                      _Float16* __restrict__ qo, _Float16* __restrict__ ko,
                      _Float16* __restrict__ vo, float* __restrict__ outf,
                      int M)
{
    __shared__ __align__(16) _Float16 Alds[128 * 64];
    __shared__ __align__(16) _Float16 Blds[128 * 64];

    const int tid  = threadIdx.x;
    const int wid  = tid >> 6;
    const int lane = tid & 63;
    const int bn   = blockIdx.x * 128;
    const int bm   = blockIdx.y * 128;
    const int wr   = wid >> 1;
    const int wc   = wid & 1;

    f32x4 acc[4][4] = {};

    const int srow  = lane >> 3;        // 0..7
    const int sseg  = lane & 7;         // 0..7 (16B segment within 128B row)

    for (int k0 = 0; k0 < KDIM; k0 += 64) {
        #pragma unroll
        for (int i = 0; i < 4; ++i) {
            const int chunk = i * 4 + wid;       // 0..15 wave-uniform
            const int row   = chunk * 8 + srow;  // 0..127
            int am = bm + row;
            am = (am < M) ? am : (M - 1);
            if (MODE == 0) {
                // fused fp32->fp16 A staging
                const float4* xs = reinterpret_cast<const float4*>(
                    Xf + (size_t)am * KDIM + k0) + sseg * 2;
                const float4 xa = xs[0];
                const float4 xb = xs[1];
                uint4 wv;
                wv.x = __builtin_bit_cast(unsigned, pack2(xa.x, xa.y));
                wv.y = __builtin_bit_cast(unsigned, pack2(xa.z, xa.w));
                wv.z = __builtin_bit_cast(unsigned, pack2(xb.x, xb.y));
                wv.w = __builtin_bit_cast(unsigned, pack2(xb.z, xb.w));
                *reinterpret_cast<uint4*>(
                    &Alds[chunk * 512 + srow * 64 + sseg * 8]) = wv;
            } else {
                const char* asrc = (const char*)(Ah + (size_t)am * KDIM + k0)
                                   + sseg * 16;
                __builtin_amdgcn_global_load_lds(
                    (const __attribute__((address_space(1))) void*)asrc,
                    (__attribute__((address_space(3))) void*)((char*)Alds + chunk * 1024),
                    16, 0, 0);
            }
            const char* bsrc = (const char*)(Bt + (size_t)(bn + row) * KDIM + k0)
                               + sseg * 16;
            __builtin_amdgcn_global_load_lds(
                (const __attribute__((address_space(1))) void*)bsrc,
                (__attribute__((address_space(3))) void*)((char*)Blds + chunk * 1024),
                16, 0, 0);
        }
        __syncthreads();
        #pragma unroll
        for (int kk = 0; kk < 64; kk += 32) {
            const int ko2 = kk + (lane >> 4) * 8;
            f16x8 af[4], bf[4];
            #pragma unroll
            for (int t = 0; t < 4; ++t) {
                af[t] = *(const f16x8*)&Alds[(wr * 64 + t * 16 + (lane & 15)) * 64 + ko2];
                bf[t] = *(const f16x8*)&Blds[(wc * 64 + t * 16 + (lane & 15)) * 64 + ko2];
            }
            #pragma unroll
            for (int fi = 0; fi < 4; ++fi)
                #pragma unroll
                for (int fj = 0; fj < 4; ++fj)
                    acc[fi][fj] = __builtin_amdgcn_mfma_f32_16x16x32_f16(
                        af[fi], bf[fj], acc[fi][fj], 0, 0, 0);
        }
        __syncthreads();
    }

    // epilogue — C/D layout: col = lane&15, row = (lane>>4)*4 + j
    const int lc  = lane & 15;
    const int lrb = (lane >> 4) * 4;
    if (MODE == 0) {
        // Coalesced store path: per (fi, fj-pair), write the 16m x 32c fp16
        // tile into per-wave LDS scratch, then each lane stores one 16B row
        // segment. All 32 cols of a pair belong to ONE head's 32 dims.
        const float scale = 0.17677669529663687f;
        _Float16* sw = Alds + wid * 640;   // 16 rows x 34 f16 (+pad), per-wave
        const int row = lane >> 2;          // 0..15
        const int seg = lane & 3;           // 0..3
        #pragma unroll
        for (int fi = 0; fi < 4; ++fi) {
            #pragma unroll
            for (int fp = 0; fp < 2; ++fp) {       // fj pair (2fp, 2fp+1)
                #pragma unroll
                for (int ff = 0; ff < 2; ++ff) {
                    const int fj = fp * 2 + ff;
                    const int c = bn + wc * 64 + fj * 16 + lc;
                    const float bv = bias[c];
                    const float scl = ((c >> 8) == 0) ? scale : 1.0f;
                    #pragma unroll
                    for (int j = 0; j < 4; ++j)
                        sw[(lrb + j) * 34 + ff * 16 + lc] =
                            (_Float16)((acc[fi][fj][j] + bv) * scl);
                }
                const int c0 = bn + wc * 64 + fp * 32;
                const int which = c0 >> 8;          // 0=q 1=k 2=v
                const int head  = (c0 >> 5) & 7;
                _Float16* dst = (which == 0) ? qo : (which == 1) ? ko : vo;
                const int m = bm + wr * 64 + fi * 16 + row;
                f16x8 vv = *(const f16x8*)&sw[row * 34 + seg * 8];
                if (m < M)
                    *(f16x8*)&dst[((size_t)head * M + m) * HD + seg * 8] = vv;
            }
        }
    } else {
        #pragma unroll
        for (int fj = 0; fj < 4; ++fj) {
            const int c = bn + wc * 64 + fj * 16 + lc;
            const float bv = bias[c];
            #pragma unroll
            for (int fi = 0; fi < 4; ++fi) {
                #pragma unroll
                for (int j = 0; j < 4; ++j) {
                    const int m = bm + wr * 64 + fi * 16 + lrb + j;
                    if (m < M)
                        outf[(size_t)m * NB + c] = acc[fi][fj][j] + bv;
                }
            }
        }
    }
}

// ---------------------------------------------------------------------------
// Attention: one query per thread, block = (head, 8h x 32w tile), single
// 34 KB LDS buffer time-shared K -> V.  T-MAJOR LDS layout:
//   unit(row, t, col) = row*(4*KCOLS) + t*KCOLS + col
// so a fixed-t read across the 32 w-lanes hits consecutive 16B units
// (conflict-free b128), and the 4 t-reads are base + immediate offsets.
// ---------------------------------------------------------------------------
#define KROWS 14
#define KCOLS 38
#define KUNITS (KROWS * KCOLS * 4)   // 2128 x 16B

__device__ __forceinline__ void stage_tile(const uint4* __restrict__ src,
                                           uint4* __restrict__ dst,
                                           int n, int r0, int w0, int tid)
{
    for (int u = tid; u < KUNITS; u += 256) {
        const int row = u / (KCOLS * 4);
        const int rem = u - row * (KCOLS * 4);
        const int col = rem >> 2;
        const int t   = rem & 3;
        int grow = r0 + row;
        if (grow > H_DIM - 1) grow = H_DIM - 1;   // clamped rows never read
        int gcol = w0 - 3 + col;
        if (gcol < 0) gcol += W_DIM;
        else if (gcol >= W_DIM) gcol -= W_DIM;
        dst[row * (KCOLS * 4) + t * KCOLS + col] =
            src[(((size_t)n * H_DIM + grow) * W_DIM + gcol) * 4 + t];
    }
}

__device__ __forceinline__ float qkdot8(uint4 kk, const h2* qh, float acc)
{
    h2 k0 = __builtin_bit_cast(h2, kk.x);
    h2 k1 = __builtin_bit_cast(h2, kk.y);
    h2 k2 = __builtin_bit_cast(h2, kk.z);
    h2 k3 = __builtin_bit_cast(h2, kk.w);
#if HAS_FDOT2
    acc = __builtin_amdgcn_fdot2(k0, qh[0], acc, false);
    acc = __builtin_amdgcn_fdot2(k1, qh[1], acc, false);
    acc = __builtin_amdgcn_fdot2(k2, qh[2], acc, false);
    acc = __builtin_amdgcn_fdot2(k3, qh[3], acc, false);
#else
    acc += (float)k0.x * (float)qh[0].x + (float)k0.y * (float)qh[0].y;
    acc += (float)k1.x * (float)qh[1].x + (float)k1.y * (float)qh[1].y;
    acc += (float)k2.x * (float)qh[2].x + (float)k2.y * (float)qh[2].y;
    acc += (float)k3.x * (float)qh[3].x + (float)k3.y * (float)qh[3].y;
#endif
    return acc;
}

__global__ __launch_bounds__(256)
void natten_attn_kernel(const _Float16* __restrict__ q,   // [8][M][32]
                        const uint4* __restrict__ kb,
                        const uint4* __restrict__ vb,
                        const float* __restrict__ rpb,    // [8][13][13]
                        _Float16* __restrict__ outh)      // [M][256]
{
    __shared__ uint4 kvs[KUNITS];
    __shared__ float rpbs[169];

    const int tid = threadIdx.x;
    const int n  = blockIdx.z;
    const int w0 = blockIdx.x * 32;
    const int h0 = blockIdx.y * 8;

    int r0 = h0 - 3;
    if (r0 < 0) r0 = 0;
    if (r0 > H_DIM - 7) r0 = H_DIM - 7;

    if (tid < 169) rpbs[tid] = rpb[n * 169 + tid];

    // ---- phase 1: stage K ----
    stage_tile(kb, kvs, n, r0, w0, tid);
    __syncthreads();

    const int hl = tid >> 5;
    const int wl = tid & 31;
    const int h = h0 + hl;
    const int w = w0 + wl;
    const bool valid = (h < H_DIM) && (w < W_DIM);

    float sc[49];
    float inv = 0.f;
    int ri0 = 0;

    if (valid) {
        int sh = h - 3;
        if (sh < 0) sh = 0;
        if (sh > H_DIM - 7) sh = H_DIM - 7;
        ri0 = sh - r0;
        const int rh0 = sh - h + 6;

        // q (pre-scaled f16) kept packed: 16 half2 = 16 VGPRs
        const uint4* qp = reinterpret_cast<const uint4*>(
            q + ((size_t)n * MPIX + (size_t)h * W_DIM + w) * HD);
        h2 qh[16];
        #pragma unroll
        for (int t = 0; t < 4; ++t) {
            const uint4 qq = qp[t];
            qh[t*4+0] = __builtin_bit_cast(h2, qq.x);
            qh[t*4+1] = __builtin_bit_cast(h2, qq.y);
            qh[t*4+2] = __builtin_bit_cast(h2, qq.z);
            qh[t*4+3] = __builtin_bit_cast(h2, qq.w);
        }

        #pragma unroll
        for (int oi = 0; oi < 7; ++oi) {
            const int rb = (ri0 + oi) * (KCOLS * 4);
            #pragma unroll
            for (int oj = 0; oj < 7; ++oj) {
                const int base = rb + wl + oj;
                float dot = rpbs[(rh0 + oi) * 13 + 3 + oj];
                dot = qkdot8(kvs[base],             qh + 0,  dot);
                dot = qkdot8(kvs[base + KCOLS],     qh + 4,  dot);
                dot = qkdot8(kvs[base + 2 * KCOLS], qh + 8,  dot);
                dot = qkdot8(kvs[base + 3 * KCOLS], qh + 12, dot);
                sc[oi * 7 + oj] = dot;
            }
        }

        float mx = sc[0];
        #pragma unroll
        for (int i = 1; i < 49; ++i) mx = fmaxf(mx, sc[i]);
        float ssum = 0.f;
        #pragma unroll
        for (int i = 0; i < 49; ++i) { sc[i] = __expf(sc[i] - mx); ssum += sc[i]; }
        inv = 1.f / ssum;
    }
    __syncthreads();

    // ---- phase 2: stage V into the same buffer ----
    stage_tile(vb, kvs, n, r0, w0, tid);
    __syncthreads();

    if (!valid) return;

    // PV: accumulate raw exp weights; normalize at the end.
    float acc[32];
    #pragma unroll
    for (int t = 0; t < 32; ++t) acc[t] = 0.f;
    #pragma unroll
    for (int oi = 0; oi < 7; ++oi) {
        const int rb = (ri0 + oi) * (KCOLS * 4);
        #pragma unroll
        for (int oj = 0; oj < 7; ++oj) {
            const int base = rb + wl + oj;
            const float a = sc[oi * 7 + oj];
            #pragma unroll
            for (int t = 0; t < 4; ++t) {
                const uint4 vv = kvs[base + t * KCOLS];
                h2 v0 = __builtin_bit_cast(h2, vv.x);
                h2 v1 = __builtin_bit_cast(h2, vv.y);
                h2 v2 = __builtin_bit_cast(h2, vv.z);
                h2 v3 = __builtin_bit_cast(h2, vv.w);
                acc[t*8+0] += a * (float)v0.x; acc[t*8+1] += a * (float)v0.y;
                acc[t*8+2] += a * (float)v1.x; acc[t*8+3] += a * (float)v1.y;
                acc[t*8+4] += a * (float)v2.x; acc[t*8+5] += a * (float)v2.y;
                acc[t*8+6] += a * (float)v3.x; acc[t*8+7] += a * (float)v3.y;
            }
        }
    }

    uint4 o[4];
    #pragma unroll
    for (int t = 0; t < 4; ++t) {
        h2 p0 = { (_Float16)(acc[t*8+0] * inv), (_Float16)(acc[t*8+1] * inv) };
        h2 p1 = { (_Float16)(acc[t*8+2] * inv), (_Float16)(acc[t*8+3] * inv) };
        h2 p2 = { (_Float16)(acc[t*8+4] * inv), (_Float16)(acc[t*8+5] * inv) };
        h2 p3 = { (_Float16)(acc[t*8+6] * inv), (_Float16)(acc[t*8+7] * inv) };
        o[t].x = __builtin_bit_cast(unsigned, p0);
        o[t].y = __builtin_bit_cast(unsigned, p1);
        o[t].z = __builtin_bit_cast(unsigned, p2);
        o[t].w = __builtin_bit_cast(unsigned, p3);
    }
    uint4* op = reinterpret_cast<uint4*>(
        outh + (((size_t)h * W_DIM + w) * CH + n * HD));
    #pragma unroll
    for (int t = 0; t < 4; ++t) op[t] = o[t];
}

// ---------------------------------------------------------------------------
extern "C" void kernel_launch(void* const* d_in, const int* in_sizes, int n_in,
                              void* d_out, int out_size, void* d_ws, size_t ws_size,
                              hipStream_t stream)
{
    const float* x      = (const float*)d_in[0];
    const float* w_qkv  = (const float*)d_in[1];
    const float* b_qkv  = (const float*)d_in[2];
    const float* rpb    = (const float*)d_in[3];
    const float* w_proj = (const float*)d_in[4];
    const float* b_proj = (const float*)d_in[5];
    float* out = (float*)d_out;

    const int M = MPIX;
    const size_t nelem = (size_t)M * KDIM;

    _Float16* Wqt = (_Float16*)d_ws;          // [768][256]
    _Float16* Wpt = Wqt + 768 * 256;          // [256][256]
    _Float16* qb  = Wpt + 256 * 256;          // [8][M][32]
    _Float16* kb  = qb  + nelem;
    _Float16* vb  = kb  + nelem;
    _Float16* ah  = vb  + nelem;              // [M][256] attn out f16

    const size_t need = (4 * nelem + 768 * 256 + 256 * 256) * sizeof(_Float16);
    if (ws_size < need) return;

    dim3 blk(256);
    convert_w_kernel<<<dim3(768, 2), blk, 0, stream>>>(w_qkv, w_proj, Wqt, Wpt);

    mfma_gemm_kernel<768, 0><<<dim3(6, 507), blk, 0, stream>>>(
        x, nullptr, Wqt, b_qkv, qb, kb, vb, nullptr, M);

    natten_attn_kernel<<<dim3(12, 23, NHEAD), blk, 0, stream>>>(
        qb, (const uint4*)kb, (const uint4*)vb, rpb, ah);

    mfma_gemm_kernel<256, 1><<<dim3(2, 507), blk, 0, stream>>>(
        nullptr, ah, Wpt, b_proj, nullptr, nullptr, nullptr, out, M);
}

// Round 10
// 225.578 us; speedup vs baseline: 1.0196x; 1.0196x over previous
//
#include <hip/hip_runtime.h>
#include <hip/hip_fp16.h>
#include <math.h>

#define H_DIM 180
#define W_DIM 360
#define CH    256
#define NHEAD 8
#define HD    32
#define MPIX  (H_DIM * W_DIM)   // 64800
#define KDIM  256

typedef _Float16 f16x8 __attribute__((ext_vector_type(8)));
typedef _Float16 h2    __attribute__((ext_vector_type(2)));
typedef float    f32x4 __attribute__((ext_vector_type(4)));

#if __has_builtin(__builtin_amdgcn_fdot2)
#define HAS_FDOT2 1
#else
#define HAS_FDOT2 0
#endif

__device__ __forceinline__ h2 pack2(float a, float b) {
#if __has_builtin(__builtin_amdgcn_cvt_pkrtz)
    return __builtin_bit_cast(h2, __builtin_amdgcn_cvt_pkrtz(a, b));
#else
    h2 r; r.x = (_Float16)a; r.y = (_Float16)b; return r;
#endif
}

// ---------------------------------------------------------------------------
// Kernel 0: fp32 -> fp16 conversions. y=0: X; y=1: w_qkv -> Wqt[768][256]
// (transposed); y=2: w_proj -> Wpt[256][256] (transposed).
// ---------------------------------------------------------------------------
__global__ __launch_bounds__(256)
void convert_kernel(const float* __restrict__ X, const float* __restrict__ Wq,
                    const float* __restrict__ Wp, _Float16* __restrict__ Xh,
                    _Float16* __restrict__ Wqt, _Float16* __restrict__ Wpt)
{
    const int tid = blockIdx.x * 256 + threadIdx.x;
    if (blockIdx.y == 0) {
        const float4* X4 = reinterpret_cast<const float4*>(X);
        const float4 a = X4[tid * 2];
        const float4 b = X4[tid * 2 + 1];
        uint4 o;
        o.x = __builtin_bit_cast(unsigned, pack2(a.x, a.y));
        o.y = __builtin_bit_cast(unsigned, pack2(a.z, a.w));
        o.z = __builtin_bit_cast(unsigned, pack2(b.x, b.y));
        o.w = __builtin_bit_cast(unsigned, pack2(b.z, b.w));
        reinterpret_cast<uint4*>(Xh)[tid] = o;
    } else if (blockIdx.y == 1) {
        if (tid < 768 * 256) {
            const int n = tid >> 8, k = tid & 255;
            Wqt[tid] = (_Float16)Wq[k * 768 + n];
        }
    } else {
        if (tid < 256 * 256) {
            const int n = tid >> 8, k = tid & 255;
            Wpt[tid] = (_Float16)Wp[k * 256 + n];
        }
    }
}

// ---------------------------------------------------------------------------
// MFMA fp16 GEMM, 128x128 tile, 4 waves (64x64 each), BK=64, K=256.
// MODE 0: qkv epilogue -> coalesced fp16 scatter via per-wave LDS transpose.
// MODE 1: proj epilogue (bias, fp32 out [M][NB]).
// ---------------------------------------------------------------------------
template<int NB, int MODE>
__global__ __launch_bounds__(256)
void mfma_gemm_kernel(const _Float16* __restrict__ A,
                      const _Float16* __restrict__ Bt,
                      const float* __restrict__ bias,
                      _Float16* __restrict__ qo, _Float16* __restrict__ ko,
                      _Float16* __restrict__ vo, float* __restrict__ outf,
                      int M)
{
    __shared__ __align__(16) _Float16 Alds[128 * 64];
    __shared__ __align__(16) _Float16 Blds[128 * 64];

    const int tid  = threadIdx.x;
    const int wid  = tid >> 6;
    const int lane = tid & 63;
    const int bn   = blockIdx.x * 128;
    const int bm   = blockIdx.y * 128;
    const int wr   = wid >> 1;
    const int wc   = wid & 1;

    f32x4 acc[4][4] = {};

    const int srow  = lane >> 3;
    const int sunit = (lane & 7) * 16;

    for (int k0 = 0; k0 < KDIM; k0 += 64) {
        #pragma unroll
        for (int i = 0; i < 4; ++i) {
            const int chunk = i * 4 + wid;
            const int row   = chunk * 8 + srow;
            int am = bm + row;
            am = (am < M) ? am : (M - 1);
            const char* asrc = (const char*)(A + (size_t)am * KDIM + k0) + sunit;
            __builtin_amdgcn_global_load_lds(
                (const __attribute__((address_space(1))) void*)asrc,
                (__attribute__((address_space(3))) void*)((char*)Alds + chunk * 1024),
                16, 0, 0);
            const char* bsrc = (const char*)(Bt + (size_t)(bn + row) * KDIM + k0) + sunit;
            __builtin_amdgcn_global_load_lds(
                (const __attribute__((address_space(1))) void*)bsrc,
                (__attribute__((address_space(3))) void*)((char*)Blds + chunk * 1024),
                16, 0, 0);
        }
        __syncthreads();
        #pragma unroll
        for (int kk = 0; kk < 64; kk += 32) {
            const int ko2 = kk + (lane >> 4) * 8;
            f16x8 af[4], bf[4];
            #pragma unroll
            for (int t = 0; t < 4; ++t) {
                af[t] = *(const f16x8*)&Alds[(wr * 64 + t * 16 + (lane & 15)) * 64 + ko2];
                bf[t] = *(const f16x8*)&Blds[(wc * 64 + t * 16 + (lane & 15)) * 64 + ko2];
            }
            #pragma unroll
            for (int fi = 0; fi < 4; ++fi)
                #pragma unroll
                for (int fj = 0; fj < 4; ++fj)
                    acc[fi][fj] = __builtin_amdgcn_mfma_f32_16x16x32_f16(
                        af[fi], bf[fj], acc[fi][fj], 0, 0, 0);
        }
        __syncthreads();
    }

    // epilogue — C/D layout: col = lane&15, row = (lane>>4)*4 + j
    const int lc  = lane & 15;
    const int lrb = (lane >> 4) * 4;
    if (MODE == 0) {
        const float scale = 0.17677669529663687f;
        _Float16* sw = Alds + wid * 640;   // 16 rows x 34 f16 (+pad), per-wave
        const int row = lane >> 2;          // 0..15
        const int seg = lane & 3;           // 0..3
        #pragma unroll
        for (int fi = 0; fi < 4; ++fi) {
            #pragma unroll
            for (int fp = 0; fp < 2; ++fp) {       // fj pair (2fp, 2fp+1)
                #pragma unroll
                for (int ff = 0; ff < 2; ++ff) {
                    const int fj = fp * 2 + ff;
                    const int c = bn + wc * 64 + fj * 16 + lc;
                    const float bv = bias[c];
                    const float scl = ((c >> 8) == 0) ? scale : 1.0f;
                    #pragma unroll
                    for (int j = 0; j < 4; ++j)
                        sw[(lrb + j) * 34 + ff * 16 + lc] =
                            (_Float16)((acc[fi][fj][j] + bv) * scl);
                }
                const int c0 = bn + wc * 64 + fp * 32;
                const int which = c0 >> 8;          // 0=q 1=k 2=v
                const int head  = (c0 >> 5) & 7;
                _Float16* dst = (which == 0) ? qo : (which == 1) ? ko : vo;
                const int m = bm + wr * 64 + fi * 16 + row;
                f16x8 vv = *(const f16x8*)&sw[row * 34 + seg * 8];
                if (m < M)
                    *(f16x8*)&dst[((size_t)head * M + m) * HD + seg * 8] = vv;
            }
        }
    } else {
        #pragma unroll
        for (int fj = 0; fj < 4; ++fj) {
            const int c = bn + wc * 64 + fj * 16 + lc;
            const float bv = bias[c];
            #pragma unroll
            for (int fi = 0; fi < 4; ++fi) {
                #pragma unroll
                for (int j = 0; j < 4; ++j) {
                    const int m = bm + wr * 64 + fi * 16 + lrb + j;
                    if (m < M)
                        outf[(size_t)m * NB + c] = acc[fi][fj][j] + bv;
                }
            }
        }
    }
}

// ---------------------------------------------------------------------------
// Attention: one query per thread, block = (head, 8h x 32w tile).
// K and V BOTH staged upfront via global_load_lds DMA (t-major linear LDS
// dest, per-lane wrapped/clamped global src), padded to 2304 units so all
// lanes stay active. ONE barrier total; t-major reads are conflict-free.
// ---------------------------------------------------------------------------
#define KROWS 14
#define KCOLS 38
#define KUNITS (KROWS * KCOLS * 4)   // 2128 x 16B
#define KUNITS_PAD 2304              // 9 x 256

__global__ __launch_bounds__(256)
void natten_attn_kernel(const _Float16* __restrict__ q,   // [8][M][32]
                        const uint4* __restrict__ kb,
                        const uint4* __restrict__ vb,
                        const float* __restrict__ rpb,    // [8][13][13]
                        _Float16* __restrict__ outh)      // [M][256]
{
    __shared__ uint4 ks[KUNITS_PAD];
    __shared__ uint4 vs[KUNITS_PAD];
    __shared__ float rpbs[169];

    const int tid = threadIdx.x;
    const int n  = blockIdx.z;
    const int w0 = blockIdx.x * 32;
    const int h0 = blockIdx.y * 8;

    int r0 = h0 - 3;
    if (r0 < 0) r0 = 0;
    if (r0 > H_DIM - 7) r0 = H_DIM - 7;

    if (tid < 169) rpbs[tid] = rpb[n * 169 + tid];

    // ---- stage K and V via DMA: 9 chunks of 256 units each ----
    {
        const int wid  = tid >> 6;
        const int lane = tid & 63;
        #pragma unroll
        for (int it = 0; it < 9; ++it) {
            const int u0 = it * 256 + wid * 64;   // wave-uniform LDS base
            const int u  = u0 + lane;
            const int row = u / (KCOLS * 4);      // 0..15 (pad rows clamped)
            const int rem = u - row * (KCOLS * 4);
            const int t   = rem / KCOLS;          // 0..3
            const int col = rem - t * KCOLS;      // 0..37
            int grow = r0 + row;
            if (grow > H_DIM - 1) grow = H_DIM - 1;
            int gcol = w0 - 3 + col;
            if (gcol < 0) gcol += W_DIM;
            else if (gcol >= W_DIM) gcol -= W_DIM;
            const size_t gidx = (((size_t)n * H_DIM + grow) * W_DIM + gcol) * 4 + t;
            __builtin_amdgcn_global_load_lds(
                (const __attribute__((address_space(1))) void*)(kb + gidx),
                (__attribute__((address_space(3))) void*)(ks + u0), 16, 0, 0);
            __builtin_amdgcn_global_load_lds(
                (const __attribute__((address_space(1))) void*)(vb + gidx),
                (__attribute__((address_space(3))) void*)(vs + u0), 16, 0, 0);
        }
    }
    __syncthreads();

    const int hl = tid >> 5;
    const int wl = tid & 31;
    const int h = h0 + hl;
    const int w = w0 + wl;
    if (h >= H_DIM || w >= W_DIM) return;   // no barriers past this point

    int sh = h - 3;
    if (sh < 0) sh = 0;
    if (sh > H_DIM - 7) sh = H_DIM - 7;
    const int ri0 = sh - r0;
    const int rh0 = sh - h + 6;

    // q (pre-scaled f16) kept packed: 16 half2 = 16 VGPRs
    const uint4* qp = reinterpret_cast<const uint4*>(
        q + ((size_t)n * MPIX + (size_t)h * W_DIM + w) * HD);
    h2 qh[16];
    #pragma unroll
    for (int t = 0; t < 4; ++t) {
        const uint4 qq = qp[t];
        qh[t*4+0] = __builtin_bit_cast(h2, qq.x);
        qh[t*4+1] = __builtin_bit_cast(h2, qq.y);
        qh[t*4+2] = __builtin_bit_cast(h2, qq.z);
        qh[t*4+3] = __builtin_bit_cast(h2, qq.w);
    }

    float sc[49];
    #pragma unroll
    for (int oi = 0; oi < 7; ++oi) {
        const int rb = (ri0 + oi) * (KCOLS * 4);
        #pragma unroll
        for (int oj = 0; oj < 7; ++oj) {
            const int base = rb + wl + oj;
            float dot = rpbs[(rh0 + oi) * 13 + 3 + oj];
            #pragma unroll
            for (int t = 0; t < 4; ++t) {
                const uint4 kk = ks[base + t * KCOLS];
                h2 k0 = __builtin_bit_cast(h2, kk.x);
                h2 k1 = __builtin_bit_cast(h2, kk.y);
                h2 k2 = __builtin_bit_cast(h2, kk.z);
                h2 k3 = __builtin_bit_cast(h2, kk.w);
#if HAS_FDOT2
                dot = __builtin_amdgcn_fdot2(k0, qh[t*4+0], dot, false);
                dot = __builtin_amdgcn_fdot2(k1, qh[t*4+1], dot, false);
                dot = __builtin_amdgcn_fdot2(k2, qh[t*4+2], dot, false);
                dot = __builtin_amdgcn_fdot2(k3, qh[t*4+3], dot, false);
#else
                dot += (float)k0.x * (float)qh[t*4+0].x + (float)k0.y * (float)qh[t*4+0].y;
                dot += (float)k1.x * (float)qh[t*4+1].x + (float)k1.y * (float)qh[t*4+1].y;
                dot += (float)k2.x * (float)qh[t*4+2].x + (float)k2.y * (float)qh[t*4+2].y;
                dot += (float)k3.x * (float)qh[t*4+3].x + (float)k3.y * (float)qh[t*4+3].y;
#endif
            }
            sc[oi * 7 + oj] = dot;
        }
    }

    float mx = sc[0];
    #pragma unroll
    for (int i = 1; i < 49; ++i) mx = fmaxf(mx, sc[i]);
    float ssum = 0.f;
    #pragma unroll
    for (int i = 0; i < 49; ++i) { sc[i] = __expf(sc[i] - mx); ssum += sc[i]; }
    const float inv = 1.f / ssum;

    // fence cross-phase LDS-read hoisting (register-pressure guard)
    __builtin_amdgcn_sched_barrier(0);

    // PV: accumulate raw exp weights; normalize at the end.
    float acc[32];
    #pragma unroll
    for (int t = 0; t < 32; ++t) acc[t] = 0.f;
    #pragma unroll
    for (int oi = 0; oi < 7; ++oi) {
        const int rb = (ri0 + oi) * (KCOLS * 4);
        #pragma unroll
        for (int oj = 0; oj < 7; ++oj) {
            const int base = rb + wl + oj;
            const float a = sc[oi * 7 + oj];
            #pragma unroll
            for (int t = 0; t < 4; ++t) {
                const uint4 vv = vs[base + t * KCOLS];
                h2 v0 = __builtin_bit_cast(h2, vv.x);
                h2 v1 = __builtin_bit_cast(h2, vv.y);
                h2 v2 = __builtin_bit_cast(h2, vv.z);
                h2 v3 = __builtin_bit_cast(h2, vv.w);
                acc[t*8+0] += a * (float)v0.x; acc[t*8+1] += a * (float)v0.y;
                acc[t*8+2] += a * (float)v1.x; acc[t*8+3] += a * (float)v1.y;
                acc[t*8+4] += a * (float)v2.x; acc[t*8+5] += a * (float)v2.y;
                acc[t*8+6] += a * (float)v3.x; acc[t*8+7] += a * (float)v3.y;
            }
        }
    }

    uint4 o[4];
    #pragma unroll
    for (int t = 0; t < 4; ++t) {
        h2 p0 = { (_Float16)(acc[t*8+0] * inv), (_Float16)(acc[t*8+1] * inv) };
        h2 p1 = { (_Float16)(acc[t*8+2] * inv), (_Float16)(acc[t*8+3] * inv) };
        h2 p2 = { (_Float16)(acc[t*8+4] * inv), (_Float16)(acc[t*8+5] * inv) };
        h2 p3 = { (_Float16)(acc[t*8+6] * inv), (_Float16)(acc[t*8+7] * inv) };
        o[t].x = __builtin_bit_cast(unsigned, p0);
        o[t].y = __builtin_bit_cast(unsigned, p1);
        o[t].z = __builtin_bit_cast(unsigned, p2);
        o[t].w = __builtin_bit_cast(unsigned, p3);
    }
    uint4* op = reinterpret_cast<uint4*>(
        outh + (((size_t)h * W_DIM + w) * CH + n * HD));
    #pragma unroll
    for (int t = 0; t < 4; ++t) op[t] = o[t];
}

// ---------------------------------------------------------------------------
extern "C" void kernel_launch(void* const* d_in, const int* in_sizes, int n_in,
                              void* d_out, int out_size, void* d_ws, size_t ws_size,
                              hipStream_t stream)
{
    const float* x      = (const float*)d_in[0];
    const float* w_qkv  = (const float*)d_in[1];
    const float* b_qkv  = (const float*)d_in[2];
    const float* rpb    = (const float*)d_in[3];
    const float* w_proj = (const float*)d_in[4];
    const float* b_proj = (const float*)d_in[5];
    float* out = (float*)d_out;

    const int M = MPIX;
    const size_t nelem = (size_t)M * KDIM;

    _Float16* Xh  = (_Float16*)d_ws;
    _Float16* Wqt = Xh  + nelem;
    _Float16* Wpt = Wqt + 768 * 256;
    _Float16* qb  = Wpt + 256 * 256;
    _Float16* kb  = qb  + nelem;
    _Float16* vb  = kb  + nelem;
    _Float16* ah  = vb  + nelem;

    const size_t need = (5 * nelem + 768 * 256 + 256 * 256) * sizeof(_Float16);
    if (ws_size < need) return;

    dim3 blk(256);
    convert_kernel<<<dim3(8100, 3), blk, 0, stream>>>(x, w_qkv, w_proj, Xh, Wqt, Wpt);

    mfma_gemm_kernel<768, 0><<<dim3(6, 507), blk, 0, stream>>>(
        Xh, Wqt, b_qkv, qb, kb, vb, nullptr, M);

    natten_attn_kernel<<<dim3(12, 23, NHEAD), blk, 0, stream>>>(
        qb, (const uint4*)kb, (const uint4*)vb, rpb, ah);

    mfma_gemm_kernel<256, 1><<<dim3(2, 507), blk, 0, stream>>>(
        ah, Wpt, b_proj, nullptr, nullptr, nullptr, out, M);
}

// Round 11
// 212.736 us; speedup vs baseline: 1.0812x; 1.0604x over previous
//
#include <hip/hip_runtime.h>
#include <hip/hip_fp16.h>
#include <math.h>

#define H_DIM 180
#define W_DIM 360
#define CH    256
#define NHEAD 8
#define HD    32
#define MPIX  (H_DIM * W_DIM)   // 64800
#define KDIM  256

typedef _Float16 f16x8 __attribute__((ext_vector_type(8)));
typedef _Float16 h2    __attribute__((ext_vector_type(2)));
typedef float    f32x4 __attribute__((ext_vector_type(4)));

#if __has_builtin(__builtin_amdgcn_fdot2)
#define HAS_FDOT2 1
#else
#define HAS_FDOT2 0
#endif

__device__ __forceinline__ h2 pack2(float a, float b) {
#if __has_builtin(__builtin_amdgcn_cvt_pkrtz)
    return __builtin_bit_cast(h2, __builtin_amdgcn_cvt_pkrtz(a, b));
#else
    h2 r; r.x = (_Float16)a; r.y = (_Float16)b; return r;
#endif
}

// ---------------------------------------------------------------------------
// Kernel 0: fp32 -> fp16 conversions. y=0: X; y=1: w_qkv -> Wqt[768][256]
// (transposed); y=2: w_proj -> Wpt[256][256] (transposed).
// ---------------------------------------------------------------------------
__global__ __launch_bounds__(256)
void convert_kernel(const float* __restrict__ X, const float* __restrict__ Wq,
                    const float* __restrict__ Wp, _Float16* __restrict__ Xh,
                    _Float16* __restrict__ Wqt, _Float16* __restrict__ Wpt)
{
    const int tid = blockIdx.x * 256 + threadIdx.x;
    if (blockIdx.y == 0) {
        const float4* X4 = reinterpret_cast<const float4*>(X);
        const float4 a = X4[tid * 2];
        const float4 b = X4[tid * 2 + 1];
        uint4 o;
        o.x = __builtin_bit_cast(unsigned, pack2(a.x, a.y));
        o.y = __builtin_bit_cast(unsigned, pack2(a.z, a.w));
        o.z = __builtin_bit_cast(unsigned, pack2(b.x, b.y));
        o.w = __builtin_bit_cast(unsigned, pack2(b.z, b.w));
        reinterpret_cast<uint4*>(Xh)[tid] = o;
    } else if (blockIdx.y == 1) {
        if (tid < 768 * 256) {
            const int n = tid >> 8, k = tid & 255;
            Wqt[tid] = (_Float16)Wq[k * 768 + n];
        }
    } else {
        if (tid < 256 * 256) {
            const int n = tid >> 8, k = tid & 255;
            Wpt[tid] = (_Float16)Wp[k * 256 + n];
        }
    }
}

// ---------------------------------------------------------------------------
// MFMA fp16 GEMM, 128x128 tile, 4 waves (64x64 each), BK=64, K=256.
// MODE 0: qkv epilogue -> coalesced fp16 scatter via per-wave LDS transpose.
// MODE 1: proj epilogue (bias, fp32 out [M][NB]).
// (round-8 verified version)
// ---------------------------------------------------------------------------
template<int NB, int MODE>
__global__ __launch_bounds__(256)
void mfma_gemm_kernel(const _Float16* __restrict__ A,
                      const _Float16* __restrict__ Bt,
                      const float* __restrict__ bias,
                      _Float16* __restrict__ qo, _Float16* __restrict__ ko,
                      _Float16* __restrict__ vo, float* __restrict__ outf,
                      int M)
{
    __shared__ __align__(16) _Float16 Alds[128 * 64];
    __shared__ __align__(16) _Float16 Blds[128 * 64];

    const int tid  = threadIdx.x;
    const int wid  = tid >> 6;
    const int lane = tid & 63;
    const int bn   = blockIdx.x * 128;
    const int bm   = blockIdx.y * 128;
    const int wr   = wid >> 1;
    const int wc   = wid & 1;

    f32x4 acc[4][4] = {};

    const int srow  = lane >> 3;
    const int sunit = (lane & 7) * 16;

    for (int k0 = 0; k0 < KDIM; k0 += 64) {
        #pragma unroll
        for (int i = 0; i < 4; ++i) {
            const int chunk = i * 4 + wid;
            const int row   = chunk * 8 + srow;
            int am = bm + row;
            am = (am < M) ? am : (M - 1);
            const char* asrc = (const char*)(A + (size_t)am * KDIM + k0) + sunit;
            __builtin_amdgcn_global_load_lds(
                (const __attribute__((address_space(1))) void*)asrc,
                (__attribute__((address_space(3))) void*)((char*)Alds + chunk * 1024),
                16, 0, 0);
            const char* bsrc = (const char*)(Bt + (size_t)(bn + row) * KDIM + k0) + sunit;
            __builtin_amdgcn_global_load_lds(
                (const __attribute__((address_space(1))) void*)bsrc,
                (__attribute__((address_space(3))) void*)((char*)Blds + chunk * 1024),
                16, 0, 0);
        }
        __syncthreads();
        #pragma unroll
        for (int kk = 0; kk < 64; kk += 32) {
            const int ko2 = kk + (lane >> 4) * 8;
            f16x8 af[4], bf[4];
            #pragma unroll
            for (int t = 0; t < 4; ++t) {
                af[t] = *(const f16x8*)&Alds[(wr * 64 + t * 16 + (lane & 15)) * 64 + ko2];
                bf[t] = *(const f16x8*)&Blds[(wc * 64 + t * 16 + (lane & 15)) * 64 + ko2];
            }
            #pragma unroll
            for (int fi = 0; fi < 4; ++fi)
                #pragma unroll
                for (int fj = 0; fj < 4; ++fj)
                    acc[fi][fj] = __builtin_amdgcn_mfma_f32_16x16x32_f16(
                        af[fi], bf[fj], acc[fi][fj], 0, 0, 0);
        }
        __syncthreads();
    }

    // epilogue — C/D layout: col = lane&15, row = (lane>>4)*4 + j
    const int lc  = lane & 15;
    const int lrb = (lane >> 4) * 4;
    if (MODE == 0) {
        const float scale = 0.17677669529663687f;
        _Float16* sw = Alds + wid * 640;   // 16 rows x 34 f16 (+pad), per-wave
        const int row = lane >> 2;          // 0..15
        const int seg = lane & 3;           // 0..3
        #pragma unroll
        for (int fi = 0; fi < 4; ++fi) {
            #pragma unroll
            for (int fp = 0; fp < 2; ++fp) {       // fj pair (2fp, 2fp+1)
                #pragma unroll
                for (int ff = 0; ff < 2; ++ff) {
                    const int fj = fp * 2 + ff;
                    const int c = bn + wc * 64 + fj * 16 + lc;
                    const float bv = bias[c];
                    const float scl = ((c >> 8) == 0) ? scale : 1.0f;
                    #pragma unroll
                    for (int j = 0; j < 4; ++j)
                        sw[(lrb + j) * 34 + ff * 16 + lc] =
                            (_Float16)((acc[fi][fj][j] + bv) * scl);
                }
                const int c0 = bn + wc * 64 + fp * 32;
                const int which = c0 >> 8;          // 0=q 1=k 2=v
                const int head  = (c0 >> 5) & 7;
                _Float16* dst = (which == 0) ? qo : (which == 1) ? ko : vo;
                const int m = bm + wr * 64 + fi * 16 + row;
                f16x8 vv = *(const f16x8*)&sw[row * 34 + seg * 8];
                if (m < M)
                    *(f16x8*)&dst[((size_t)head * M + m) * HD + seg * 8] = vv;
            }
        }
    } else {
        #pragma unroll
        for (int fj = 0; fj < 4; ++fj) {
            const int c = bn + wc * 64 + fj * 16 + lc;
            const float bv = bias[c];
            #pragma unroll
            for (int fi = 0; fi < 4; ++fi) {
                #pragma unroll
                for (int j = 0; j < 4; ++j) {
                    const int m = bm + wr * 64 + fi * 16 + lrb + j;
                    if (m < M)
                        outf[(size_t)m * NB + c] = acc[fi][fj][j] + bv;
                }
            }
        }
    }
}

// ---------------------------------------------------------------------------
// Attention: one query per thread, block = (head, 8h x 32w tile).
// Single time-shared buffer (37.5 KB -> 4 blocks/CU), staged K then V via
// global_load_lds DMA (t-major layout is lane-linear so DMA dest is legal).
// T-major reads are bank-conflict-free. Softmax without max-subtraction
// (scores O(1); verified rounds 6/7, absmax unchanged).
// ---------------------------------------------------------------------------
#define KROWS 14
#define KCOLS 38
#define KUNITS (KROWS * KCOLS * 4)   // 2128 x 16B
#define KUNITS_PAD 2304              // 9 x 256 (pad rows clamp-read, never used)

__device__ __forceinline__ void stage_dma(const uint4* __restrict__ src,
                                          uint4* __restrict__ dstlds,
                                          int n, int r0, int w0, int tid)
{
    const int wid  = tid >> 6;
    const int lane = tid & 63;
    #pragma unroll
    for (int it = 0; it < 9; ++it) {
        const int u0 = it * 256 + wid * 64;   // wave-uniform LDS base
        const int u  = u0 + lane;
        const int row = u / (KCOLS * 4);      // t-major: u = row*152 + t*38 + col
        const int rem = u - row * (KCOLS * 4);
        const int t   = rem / KCOLS;
        const int col = rem - t * KCOLS;
        int grow = r0 + row;
        if (grow > H_DIM - 1) grow = H_DIM - 1;
        int gcol = w0 - 3 + col;
        if (gcol < 0) gcol += W_DIM;
        else if (gcol >= W_DIM) gcol -= W_DIM;
        const size_t gidx = (((size_t)n * H_DIM + grow) * W_DIM + gcol) * 4 + t;
        __builtin_amdgcn_global_load_lds(
            (const __attribute__((address_space(1))) void*)(src + gidx),
            (__attribute__((address_space(3))) void*)(dstlds + u0), 16, 0, 0);
    }
}

__global__ __launch_bounds__(256)
void natten_attn_kernel(const _Float16* __restrict__ q,   // [8][M][32]
                        const uint4* __restrict__ kb,
                        const uint4* __restrict__ vb,
                        const float* __restrict__ rpb,    // [8][13][13]
                        _Float16* __restrict__ outh)      // [M][256]
{
    __shared__ uint4 kvs[KUNITS_PAD];
    __shared__ float rpbs[169];

    const int tid = threadIdx.x;
    const int n  = blockIdx.z;
    const int w0 = blockIdx.x * 32;
    const int h0 = blockIdx.y * 8;

    int r0 = h0 - 3;
    if (r0 < 0) r0 = 0;
    if (r0 > H_DIM - 7) r0 = H_DIM - 7;

    if (tid < 169) rpbs[tid] = rpb[n * 169 + tid];

    // ---- phase 1: stage K via DMA ----
    stage_dma(kb, kvs, n, r0, w0, tid);
    __syncthreads();

    const int hl = tid >> 5;
    const int wl = tid & 31;
    const int h = h0 + hl;
    const int w = w0 + wl;
    const bool valid = (h < H_DIM) && (w < W_DIM);

    float sc[49];
    float inv = 0.f;
    int ri0 = 0;

    if (valid) {
        int sh = h - 3;
        if (sh < 0) sh = 0;
        if (sh > H_DIM - 7) sh = H_DIM - 7;
        ri0 = sh - r0;
        const int rh0 = sh - h + 6;

        // q (pre-scaled f16) kept packed: 16 half2 = 16 VGPRs
        const uint4* qp = reinterpret_cast<const uint4*>(
            q + ((size_t)n * MPIX + (size_t)h * W_DIM + w) * HD);
        h2 qh[16];
        #pragma unroll
        for (int t = 0; t < 4; ++t) {
            const uint4 qq = qp[t];
            qh[t*4+0] = __builtin_bit_cast(h2, qq.x);
            qh[t*4+1] = __builtin_bit_cast(h2, qq.y);
            qh[t*4+2] = __builtin_bit_cast(h2, qq.z);
            qh[t*4+3] = __builtin_bit_cast(h2, qq.w);
        }

        #pragma unroll
        for (int oi = 0; oi < 7; ++oi) {
            const int rb = (ri0 + oi) * (KCOLS * 4);
            #pragma unroll
            for (int oj = 0; oj < 7; ++oj) {
                const int base = rb + wl + oj;
                float dot = rpbs[(rh0 + oi) * 13 + 3 + oj];
                #pragma unroll
                for (int t = 0; t < 4; ++t) {
                    const uint4 kk = kvs[base + t * KCOLS];
                    h2 k0 = __builtin_bit_cast(h2, kk.x);
                    h2 k1 = __builtin_bit_cast(h2, kk.y);
                    h2 k2 = __builtin_bit_cast(h2, kk.z);
                    h2 k3 = __builtin_bit_cast(h2, kk.w);
#if HAS_FDOT2
                    dot = __builtin_amdgcn_fdot2(k0, qh[t*4+0], dot, false);
                    dot = __builtin_amdgcn_fdot2(k1, qh[t*4+1], dot, false);
                    dot = __builtin_amdgcn_fdot2(k2, qh[t*4+2], dot, false);
                    dot = __builtin_amdgcn_fdot2(k3, qh[t*4+3], dot, false);
#else
                    dot += (float)k0.x * (float)qh[t*4+0].x + (float)k0.y * (float)qh[t*4+0].y;
                    dot += (float)k1.x * (float)qh[t*4+1].x + (float)k1.y * (float)qh[t*4+1].y;
                    dot += (float)k2.x * (float)qh[t*4+2].x + (float)k2.y * (float)qh[t*4+2].y;
                    dot += (float)k3.x * (float)qh[t*4+3].x + (float)k3.y * (float)qh[t*4+3].y;
#endif
                }
                sc[oi * 7 + oj] = dot;
            }
        }

        // softmax WITHOUT max-subtraction (scores O(1), fp32 exp headroom)
        float ssum = 0.f;
        #pragma unroll
        for (int i = 0; i < 49; ++i) { sc[i] = __expf(sc[i]); ssum += sc[i]; }
        inv = 1.f / ssum;
    }
    __syncthreads();

    // ---- phase 2: stage V via DMA into the same buffer ----
    stage_dma(vb, kvs, n, r0, w0, tid);
    __syncthreads();

    if (!valid) return;   // no barriers past this point

    // PV: accumulate raw exp weights; normalize at the end.
    float acc[32];
    #pragma unroll
    for (int t = 0; t < 32; ++t) acc[t] = 0.f;
    #pragma unroll
    for (int oi = 0; oi < 7; ++oi) {
        const int rb = (ri0 + oi) * (KCOLS * 4);
        #pragma unroll
        for (int oj = 0; oj < 7; ++oj) {
            const int base = rb + wl + oj;
            const float a = sc[oi * 7 + oj];
            #pragma unroll
            for (int t = 0; t < 4; ++t) {
                const uint4 vv = kvs[base + t * KCOLS];
                h2 v0 = __builtin_bit_cast(h2, vv.x);
                h2 v1 = __builtin_bit_cast(h2, vv.y);
                h2 v2 = __builtin_bit_cast(h2, vv.z);
                h2 v3 = __builtin_bit_cast(h2, vv.w);
                acc[t*8+0] += a * (float)v0.x; acc[t*8+1] += a * (float)v0.y;
                acc[t*8+2] += a * (float)v1.x; acc[t*8+3] += a * (float)v1.y;
                acc[t*8+4] += a * (float)v2.x; acc[t*8+5] += a * (float)v2.y;
                acc[t*8+6] += a * (float)v3.x; acc[t*8+7] += a * (float)v3.y;
            }
        }
    }

    uint4 o[4];
    #pragma unroll
    for (int t = 0; t < 4; ++t) {
        h2 p0 = { (_Float16)(acc[t*8+0] * inv), (_Float16)(acc[t*8+1] * inv) };
        h2 p1 = { (_Float16)(acc[t*8+2] * inv), (_Float16)(acc[t*8+3] * inv) };
        h2 p2 = { (_Float16)(acc[t*8+4] * inv), (_Float16)(acc[t*8+5] * inv) };
        h2 p3 = { (_Float16)(acc[t*8+6] * inv), (_Float16)(acc[t*8+7] * inv) };
        o[t].x = __builtin_bit_cast(unsigned, p0);
        o[t].y = __builtin_bit_cast(unsigned, p1);
        o[t].z = __builtin_bit_cast(unsigned, p2);
        o[t].w = __builtin_bit_cast(unsigned, p3);
    }
    uint4* op = reinterpret_cast<uint4*>(
        outh + (((size_t)h * W_DIM + w) * CH + n * HD));
    #pragma unroll
    for (int t = 0; t < 4; ++t) op[t] = o[t];
}

// ---------------------------------------------------------------------------
extern "C" void kernel_launch(void* const* d_in, const int* in_sizes, int n_in,
                              void* d_out, int out_size, void* d_ws, size_t ws_size,
                              hipStream_t stream)
{
    const float* x      = (const float*)d_in[0];
    const float* w_qkv  = (const float*)d_in[1];
    const float* b_qkv  = (const float*)d_in[2];
    const float* rpb    = (const float*)d_in[3];
    const float* w_proj = (const float*)d_in[4];
    const float* b_proj = (const float*)d_in[5];
    float* out = (float*)d_out;

    const int M = MPIX;
    const size_t nelem = (size_t)M * KDIM;

    _Float16* Xh  = (_Float16*)d_ws;
    _Float16* Wqt = Xh  + nelem;
    _Float16* Wpt = Wqt + 768 * 256;
    _Float16* qb  = Wpt + 256 * 256;
    _Float16* kb  = qb  + nelem;
    _Float16* vb  = kb  + nelem;
    _Float16* ah  = vb  + nelem;

    const size_t need = (5 * nelem + 768 * 256 + 256 * 256) * sizeof(_Float16);
    if (ws_size < need) return;

    dim3 blk(256);
    convert_kernel<<<dim3(8100, 3), blk, 0, stream>>>(x, w_qkv, w_proj, Xh, Wqt, Wpt);

    mfma_gemm_kernel<768, 0><<<dim3(6, 507), blk, 0, stream>>>(
        Xh, Wqt, b_qkv, qb, kb, vb, nullptr, M);

    natten_attn_kernel<<<dim3(12, 23, NHEAD), blk, 0, stream>>>(
        qb, (const uint4*)kb, (const uint4*)vb, rpb, ah);

    mfma_gemm_kernel<256, 1><<<dim3(2, 507), blk, 0, stream>>>(
        ah, Wpt, b_proj, nullptr, nullptr, nullptr, out, M);
}

// Round 12
// 197.890 us; speedup vs baseline: 1.1623x; 1.0750x over previous
//
#include <hip/hip_runtime.h>
#include <hip/hip_fp16.h>
#include <math.h>

#define H_DIM 180
#define W_DIM 360
#define CH    256
#define NHEAD 8
#define HD    32
#define MPIX  (H_DIM * W_DIM)   // 64800
#define KDIM  256

typedef _Float16 f16x8 __attribute__((ext_vector_type(8)));
typedef _Float16 h2    __attribute__((ext_vector_type(2)));
typedef float    f32x4 __attribute__((ext_vector_type(4)));

#if __has_builtin(__builtin_amdgcn_fdot2)
#define HAS_FDOT2 1
#else
#define HAS_FDOT2 0
#endif

__device__ __forceinline__ h2 pack2(float a, float b) {
#if __has_builtin(__builtin_amdgcn_cvt_pkrtz)
    return __builtin_bit_cast(h2, __builtin_amdgcn_cvt_pkrtz(a, b));
#else
    h2 r; r.x = (_Float16)a; r.y = (_Float16)b; return r;
#endif
}

// ---------------------------------------------------------------------------
// Kernel 0: fp32 -> fp16 conversions. y=0: X; y=1: w_qkv -> Wqt[768][256]
// (transposed); y=2: w_proj -> Wpt[256][256] (transposed).
// ---------------------------------------------------------------------------
__global__ __launch_bounds__(256)
void convert_kernel(const float* __restrict__ X, const float* __restrict__ Wq,
                    const float* __restrict__ Wp, _Float16* __restrict__ Xh,
                    _Float16* __restrict__ Wqt, _Float16* __restrict__ Wpt)
{
    const int tid = blockIdx.x * 256 + threadIdx.x;
    if (blockIdx.y == 0) {
        const float4* X4 = reinterpret_cast<const float4*>(X);
        const float4 a = X4[tid * 2];
        const float4 b = X4[tid * 2 + 1];
        uint4 o;
        o.x = __builtin_bit_cast(unsigned, pack2(a.x, a.y));
        o.y = __builtin_bit_cast(unsigned, pack2(a.z, a.w));
        o.z = __builtin_bit_cast(unsigned, pack2(b.x, b.y));
        o.w = __builtin_bit_cast(unsigned, pack2(b.z, b.w));
        reinterpret_cast<uint4*>(Xh)[tid] = o;
    } else if (blockIdx.y == 1) {
        if (tid < 768 * 256) {
            const int n = tid >> 8, k = tid & 255;
            Wqt[tid] = (_Float16)Wq[k * 768 + n];
        }
    } else {
        if (tid < 256 * 256) {
            const int n = tid >> 8, k = tid & 255;
            Wpt[tid] = (_Float16)Wp[k * 256 + n];
        }
    }
}

// ---------------------------------------------------------------------------
// MFMA fp16 GEMM, 128x128 tile, 4 waves (64x64 each), BK=64, K=256.
// MODE 0: qkv epilogue -> coalesced fp16 scatter via per-wave LDS transpose.
// MODE 1: proj epilogue (bias, fp32 out [M][NB]).
// (round-8 verified version)
// ---------------------------------------------------------------------------
template<int NB, int MODE>
__global__ __launch_bounds__(256)
void mfma_gemm_kernel(const _Float16* __restrict__ A,
                      const _Float16* __restrict__ Bt,
                      const float* __restrict__ bias,
                      _Float16* __restrict__ qo, _Float16* __restrict__ ko,
                      _Float16* __restrict__ vo, float* __restrict__ outf,
                      int M)
{
    __shared__ __align__(16) _Float16 Alds[128 * 64];
    __shared__ __align__(16) _Float16 Blds[128 * 64];

    const int tid  = threadIdx.x;
    const int wid  = tid >> 6;
    const int lane = tid & 63;
    const int bn   = blockIdx.x * 128;
    const int bm   = blockIdx.y * 128;
    const int wr   = wid >> 1;
    const int wc   = wid & 1;

    f32x4 acc[4][4] = {};

    const int srow  = lane >> 3;
    const int sunit = (lane & 7) * 16;

    for (int k0 = 0; k0 < KDIM; k0 += 64) {
        #pragma unroll
        for (int i = 0; i < 4; ++i) {
            const int chunk = i * 4 + wid;
            const int row   = chunk * 8 + srow;
            int am = bm + row;
            am = (am < M) ? am : (M - 1);
            const char* asrc = (const char*)(A + (size_t)am * KDIM + k0) + sunit;
            __builtin_amdgcn_global_load_lds(
                (const __attribute__((address_space(1))) void*)asrc,
                (__attribute__((address_space(3))) void*)((char*)Alds + chunk * 1024),
                16, 0, 0);
            const char* bsrc = (const char*)(Bt + (size_t)(bn + row) * KDIM + k0) + sunit;
            __builtin_amdgcn_global_load_lds(
                (const __attribute__((address_space(1))) void*)bsrc,
                (__attribute__((address_space(3))) void*)((char*)Blds + chunk * 1024),
                16, 0, 0);
        }
        __syncthreads();
        #pragma unroll
        for (int kk = 0; kk < 64; kk += 32) {
            const int ko2 = kk + (lane >> 4) * 8;
            f16x8 af[4], bf[4];
            #pragma unroll
            for (int t = 0; t < 4; ++t) {
                af[t] = *(const f16x8*)&Alds[(wr * 64 + t * 16 + (lane & 15)) * 64 + ko2];
                bf[t] = *(const f16x8*)&Blds[(wc * 64 + t * 16 + (lane & 15)) * 64 + ko2];
            }
            #pragma unroll
            for (int fi = 0; fi < 4; ++fi)
                #pragma unroll
                for (int fj = 0; fj < 4; ++fj)
                    acc[fi][fj] = __builtin_amdgcn_mfma_f32_16x16x32_f16(
                        af[fi], bf[fj], acc[fi][fj], 0, 0, 0);
        }
        __syncthreads();
    }

    // epilogue — C/D layout: col = lane&15, row = (lane>>4)*4 + j
    const int lc  = lane & 15;
    const int lrb = (lane >> 4) * 4;
    if (MODE == 0) {
        const float scale = 0.17677669529663687f;
        _Float16* sw = Alds + wid * 640;   // 16 rows x 34 f16 (+pad), per-wave
        const int row = lane >> 2;          // 0..15
        const int seg = lane & 3;           // 0..3
        #pragma unroll
        for (int fi = 0; fi < 4; ++fi) {
            #pragma unroll
            for (int fp = 0; fp < 2; ++fp) {       // fj pair (2fp, 2fp+1)
                #pragma unroll
                for (int ff = 0; ff < 2; ++ff) {
                    const int fj = fp * 2 + ff;
                    const int c = bn + wc * 64 + fj * 16 + lc;
                    const float bv = bias[c];
                    const float scl = ((c >> 8) == 0) ? scale : 1.0f;
                    #pragma unroll
                    for (int j = 0; j < 4; ++j)
                        sw[(lrb + j) * 34 + ff * 16 + lc] =
                            (_Float16)((acc[fi][fj][j] + bv) * scl);
                }
                const int c0 = bn + wc * 64 + fp * 32;
                const int which = c0 >> 8;          // 0=q 1=k 2=v
                const int head  = (c0 >> 5) & 7;
                _Float16* dst = (which == 0) ? qo : (which == 1) ? ko : vo;
                const int m = bm + wr * 64 + fi * 16 + row;
                f16x8 vv = *(const f16x8*)&sw[row * 34 + seg * 8];
                if (m < M)
                    *(f16x8*)&dst[((size_t)head * M + m) * HD + seg * 8] = vv;
            }
        }
    } else {
        #pragma unroll
        for (int fj = 0; fj < 4; ++fj) {
            const int c = bn + wc * 64 + fj * 16 + lc;
            const float bv = bias[c];
            #pragma unroll
            for (int fi = 0; fi < 4; ++fi) {
                #pragma unroll
                for (int j = 0; j < 4; ++j) {
                    const int m = bm + wr * 64 + fi * 16 + lrb + j;
                    if (m < M)
                        outf[(size_t)m * NB + c] = acc[fi][fj][j] + bv;
                }
            }
        }
    }
}

// ---------------------------------------------------------------------------
// Attention: one query per thread, block = (head, 8h x 32w tile).
// Single time-shared buffer (37.5 KB -> 4 blocks/CU), staged K then V via
// global_load_lds DMA, t-major conflict-free layout, no max-subtraction.
// This round: q-load hoisted above barrier 1; softmax exp/sum moved into the
// V-DMA shadow (between issue and drain); QK dot split into 4 ILP chains.
// ---------------------------------------------------------------------------
#define KROWS 14
#define KCOLS 38
#define KUNITS (KROWS * KCOLS * 4)   // 2128 x 16B
#define KUNITS_PAD 2304              // 9 x 256 (pad rows clamp-read, never used)

__device__ __forceinline__ void stage_dma(const uint4* __restrict__ src,
                                          uint4* __restrict__ dstlds,
                                          int n, int r0, int w0, int tid)
{
    const int wid  = tid >> 6;
    const int lane = tid & 63;
    #pragma unroll
    for (int it = 0; it < 9; ++it) {
        const int u0 = it * 256 + wid * 64;   // wave-uniform LDS base
        const int u  = u0 + lane;
        const int row = u / (KCOLS * 4);      // t-major: u = row*152 + t*38 + col
        const int rem = u - row * (KCOLS * 4);
        const int t   = rem / KCOLS;
        const int col = rem - t * KCOLS;
        int grow = r0 + row;
        if (grow > H_DIM - 1) grow = H_DIM - 1;
        int gcol = w0 - 3 + col;
        if (gcol < 0) gcol += W_DIM;
        else if (gcol >= W_DIM) gcol -= W_DIM;
        const size_t gidx = (((size_t)n * H_DIM + grow) * W_DIM + gcol) * 4 + t;
        __builtin_amdgcn_global_load_lds(
            (const __attribute__((address_space(1))) void*)(src + gidx),
            (__attribute__((address_space(3))) void*)(dstlds + u0), 16, 0, 0);
    }
}

__global__ __launch_bounds__(256)
void natten_attn_kernel(const _Float16* __restrict__ q,   // [8][M][32]
                        const uint4* __restrict__ kb,
                        const uint4* __restrict__ vb,
                        const float* __restrict__ rpb,    // [8][13][13]
                        _Float16* __restrict__ outh)      // [M][256]
{
    __shared__ uint4 kvs[KUNITS_PAD];
    __shared__ float rpbs[169];

    const int tid = threadIdx.x;
    const int n  = blockIdx.z;
    const int w0 = blockIdx.x * 32;
    const int h0 = blockIdx.y * 8;

    int r0 = h0 - 3;
    if (r0 < 0) r0 = 0;
    if (r0 > H_DIM - 7) r0 = H_DIM - 7;

    if (tid < 169) rpbs[tid] = rpb[n * 169 + tid];

    const int hl = tid >> 5;
    const int wl = tid & 31;
    const int h = h0 + hl;
    const int w = w0 + wl;
    const bool valid = (h < H_DIM) && (w < W_DIM);

    // ---- q global load issued BEFORE staging: completes under the DMA wait
    const int ha = (h < H_DIM) ? h : H_DIM - 1;
    const int wa = (w < W_DIM) ? w : W_DIM - 1;
    const uint4* qp = reinterpret_cast<const uint4*>(
        q + ((size_t)n * MPIX + (size_t)ha * W_DIM + wa) * HD);
    uint4 q0 = qp[0], q1 = qp[1], q2 = qp[2], q3 = qp[3];

    // ---- phase 1: stage K via DMA ----
    stage_dma(kb, kvs, n, r0, w0, tid);
    __syncthreads();

    h2 qh[16];
    qh[0]  = __builtin_bit_cast(h2, q0.x); qh[1]  = __builtin_bit_cast(h2, q0.y);
    qh[2]  = __builtin_bit_cast(h2, q0.z); qh[3]  = __builtin_bit_cast(h2, q0.w);
    qh[4]  = __builtin_bit_cast(h2, q1.x); qh[5]  = __builtin_bit_cast(h2, q1.y);
    qh[6]  = __builtin_bit_cast(h2, q1.z); qh[7]  = __builtin_bit_cast(h2, q1.w);
    qh[8]  = __builtin_bit_cast(h2, q2.x); qh[9]  = __builtin_bit_cast(h2, q2.y);
    qh[10] = __builtin_bit_cast(h2, q2.z); qh[11] = __builtin_bit_cast(h2, q2.w);
    qh[12] = __builtin_bit_cast(h2, q3.x); qh[13] = __builtin_bit_cast(h2, q3.y);
    qh[14] = __builtin_bit_cast(h2, q3.z); qh[15] = __builtin_bit_cast(h2, q3.w);

    float sc[49];
    int ri0 = 0;

    if (valid) {
        int sh = h - 3;
        if (sh < 0) sh = 0;
        if (sh > H_DIM - 7) sh = H_DIM - 7;
        ri0 = sh - r0;
        const int rh0 = sh - h + 6;

        #pragma unroll
        for (int oi = 0; oi < 7; ++oi) {
            const int rb = (ri0 + oi) * (KCOLS * 4);
            #pragma unroll
            for (int oj = 0; oj < 7; ++oj) {
                const int base = rb + wl + oj;
                // 4 independent partial-dot chains (ILP over the 4 ds_reads)
                float d0 = 0.f, d1 = 0.f, d2 = 0.f, d3 = 0.f;
                const uint4 ku0 = kvs[base];
                const uint4 ku1 = kvs[base + KCOLS];
                const uint4 ku2 = kvs[base + 2 * KCOLS];
                const uint4 ku3 = kvs[base + 3 * KCOLS];
#if HAS_FDOT2
                d0 = __builtin_amdgcn_fdot2(__builtin_bit_cast(h2, ku0.x), qh[0],  d0, false);
                d1 = __builtin_amdgcn_fdot2(__builtin_bit_cast(h2, ku1.x), qh[4],  d1, false);
                d2 = __builtin_amdgcn_fdot2(__builtin_bit_cast(h2, ku2.x), qh[8],  d2, false);
                d3 = __builtin_amdgcn_fdot2(__builtin_bit_cast(h2, ku3.x), qh[12], d3, false);
                d0 = __builtin_amdgcn_fdot2(__builtin_bit_cast(h2, ku0.y), qh[1],  d0, false);
                d1 = __builtin_amdgcn_fdot2(__builtin_bit_cast(h2, ku1.y), qh[5],  d1, false);
                d2 = __builtin_amdgcn_fdot2(__builtin_bit_cast(h2, ku2.y), qh[9],  d2, false);
                d3 = __builtin_amdgcn_fdot2(__builtin_bit_cast(h2, ku3.y), qh[13], d3, false);
                d0 = __builtin_amdgcn_fdot2(__builtin_bit_cast(h2, ku0.z), qh[2],  d0, false);
                d1 = __builtin_amdgcn_fdot2(__builtin_bit_cast(h2, ku1.z), qh[6],  d1, false);
                d2 = __builtin_amdgcn_fdot2(__builtin_bit_cast(h2, ku2.z), qh[10], d2, false);
                d3 = __builtin_amdgcn_fdot2(__builtin_bit_cast(h2, ku3.z), qh[14], d3, false);
                d0 = __builtin_amdgcn_fdot2(__builtin_bit_cast(h2, ku0.w), qh[3],  d0, false);
                d1 = __builtin_amdgcn_fdot2(__builtin_bit_cast(h2, ku1.w), qh[7],  d1, false);
                d2 = __builtin_amdgcn_fdot2(__builtin_bit_cast(h2, ku2.w), qh[11], d2, false);
                d3 = __builtin_amdgcn_fdot2(__builtin_bit_cast(h2, ku3.w), qh[15], d3, false);
#else
                {
                    h2 a, b;
                    a = __builtin_bit_cast(h2, ku0.x); b = qh[0];
                    d0 += (float)a.x * (float)b.x + (float)a.y * (float)b.y;
                    a = __builtin_bit_cast(h2, ku0.y); b = qh[1];
                    d0 += (float)a.x * (float)b.x + (float)a.y * (float)b.y;
                    a = __builtin_bit_cast(h2, ku0.z); b = qh[2];
                    d0 += (float)a.x * (float)b.x + (float)a.y * (float)b.y;
                    a = __builtin_bit_cast(h2, ku0.w); b = qh[3];
                    d0 += (float)a.x * (float)b.x + (float)a.y * (float)b.y;
                    a = __builtin_bit_cast(h2, ku1.x); b = qh[4];
                    d1 += (float)a.x * (float)b.x + (float)a.y * (float)b.y;
                    a = __builtin_bit_cast(h2, ku1.y); b = qh[5];
                    d1 += (float)a.x * (float)b.x + (float)a.y * (float)b.y;
                    a = __builtin_bit_cast(h2, ku1.z); b = qh[6];
                    d1 += (float)a.x * (float)b.x + (float)a.y * (float)b.y;
                    a = __builtin_bit_cast(h2, ku1.w); b = qh[7];
                    d1 += (float)a.x * (float)b.x + (float)a.y * (float)b.y;
                    a = __builtin_bit_cast(h2, ku2.x); b = qh[8];
                    d2 += (float)a.x * (float)b.x + (float)a.y * (float)b.y;
                    a = __builtin_bit_cast(h2, ku2.y); b = qh[9];
                    d2 += (float)a.x * (float)b.x + (float)a.y * (float)b.y;
                    a = __builtin_bit_cast(h2, ku2.z); b = qh[10];
                    d2 += (float)a.x * (float)b.x + (float)a.y * (float)b.y;
                    a = __builtin_bit_cast(h2, ku2.w); b = qh[11];
                    d2 += (float)a.x * (float)b.x + (float)a.y * (float)b.y;
                    a = __builtin_bit_cast(h2, ku3.x); b = qh[12];
                    d3 += (float)a.x * (float)b.x + (float)a.y * (float)b.y;
                    a = __builtin_bit_cast(h2, ku3.y); b = qh[13];
                    d3 += (float)a.x * (float)b.x + (float)a.y * (float)b.y;
                    a = __builtin_bit_cast(h2, ku3.z); b = qh[14];
                    d3 += (float)a.x * (float)b.x + (float)a.y * (float)b.y;
                    a = __builtin_bit_cast(h2, ku3.w); b = qh[15];
                    d3 += (float)a.x * (float)b.x + (float)a.y * (float)b.y;
                }
#endif
                sc[oi * 7 + oj] = ((d0 + d1) + (d2 + d3))
                                + rpbs[(rh0 + oi) * 13 + 3 + oj];
            }
        }
    }
    __syncthreads();

    // ---- phase 2: ISSUE V DMA, then do softmax in the DMA shadow ----
    stage_dma(vb, kvs, n, r0, w0, tid);

    float inv = 0.f;
    if (valid) {
        // softmax WITHOUT max-subtraction (scores O(1), fp32 exp headroom);
        // pure register/trans work — overlaps the in-flight global_load_lds.
        float ssum = 0.f;
        #pragma unroll
        for (int i = 0; i < 49; ++i) { sc[i] = __expf(sc[i]); ssum += sc[i]; }
        inv = 1.f / ssum;
    }
    __syncthreads();

    if (!valid) return;   // no barriers past this point

    // PV: accumulate raw exp weights; normalize at the end.
    float acc[32];
    #pragma unroll
    for (int t = 0; t < 32; ++t) acc[t] = 0.f;
    #pragma unroll
    for (int oi = 0; oi < 7; ++oi) {
        const int rb = (ri0 + oi) * (KCOLS * 4);
        #pragma unroll
        for (int oj = 0; oj < 7; ++oj) {
            const int base = rb + wl + oj;
            const float a = sc[oi * 7 + oj];
            #pragma unroll
            for (int t = 0; t < 4; ++t) {
                const uint4 vv = kvs[base + t * KCOLS];
                h2 v0 = __builtin_bit_cast(h2, vv.x);
                h2 v1 = __builtin_bit_cast(h2, vv.y);
                h2 v2 = __builtin_bit_cast(h2, vv.z);
                h2 v3 = __builtin_bit_cast(h2, vv.w);
                acc[t*8+0] += a * (float)v0.x; acc[t*8+1] += a * (float)v0.y;
                acc[t*8+2] += a * (float)v1.x; acc[t*8+3] += a * (float)v1.y;
                acc[t*8+4] += a * (float)v2.x; acc[t*8+5] += a * (float)v2.y;
                acc[t*8+6] += a * (float)v3.x; acc[t*8+7] += a * (float)v3.y;
            }
        }
    }

    uint4 o[4];
    #pragma unroll
    for (int t = 0; t < 4; ++t) {
        h2 p0 = { (_Float16)(acc[t*8+0] * inv), (_Float16)(acc[t*8+1] * inv) };
        h2 p1 = { (_Float16)(acc[t*8+2] * inv), (_Float16)(acc[t*8+3] * inv) };
        h2 p2 = { (_Float16)(acc[t*8+4] * inv), (_Float16)(acc[t*8+5] * inv) };
        h2 p3 = { (_Float16)(acc[t*8+6] * inv), (_Float16)(acc[t*8+7] * inv) };
        o[t].x = __builtin_bit_cast(unsigned, p0);
        o[t].y = __builtin_bit_cast(unsigned, p1);
        o[t].z = __builtin_bit_cast(unsigned, p2);
        o[t].w = __builtin_bit_cast(unsigned, p3);
    }
    uint4* op = reinterpret_cast<uint4*>(
        outh + (((size_t)h * W_DIM + w) * CH + n * HD));
    #pragma unroll
    for (int t = 0; t < 4; ++t) op[t] = o[t];
}

// ---------------------------------------------------------------------------
extern "C" void kernel_launch(void* const* d_in, const int* in_sizes, int n_in,
                              void* d_out, int out_size, void* d_ws, size_t ws_size,
                              hipStream_t stream)
{
    const float* x      = (const float*)d_in[0];
    const float* w_qkv  = (const float*)d_in[1];
    const float* b_qkv  = (const float*)d_in[2];
    const float* rpb    = (const float*)d_in[3];
    const float* w_proj = (const float*)d_in[4];
    const float* b_proj = (const float*)d_in[5];
    float* out = (float*)d_out;

    const int M = MPIX;
    const size_t nelem = (size_t)M * KDIM;

    _Float16* Xh  = (_Float16*)d_ws;
    _Float16* Wqt = Xh  + nelem;
    _Float16* Wpt = Wqt + 768 * 256;
    _Float16* qb  = Wpt + 256 * 256;
    _Float16* kb  = qb  + nelem;
    _Float16* vb  = kb  + nelem;
    _Float16* ah  = vb  + nelem;

    const size_t need = (5 * nelem + 768 * 256 + 256 * 256) * sizeof(_Float16);
    if (ws_size < need) return;

    dim3 blk(256);
    convert_kernel<<<dim3(8100, 3), blk, 0, stream>>>(x, w_qkv, w_proj, Xh, Wqt, Wpt);

    mfma_gemm_kernel<768, 0><<<dim3(6, 507), blk, 0, stream>>>(
        Xh, Wqt, b_qkv, qb, kb, vb, nullptr, M);

    natten_attn_kernel<<<dim3(12, 23, NHEAD), blk, 0, stream>>>(
        qb, (const uint4*)kb, (const uint4*)vb, rpb, ah);

    mfma_gemm_kernel<256, 1><<<dim3(2, 507), blk, 0, stream>>>(
        ah, Wpt, b_proj, nullptr, nullptr, nullptr, out, M);
}